// Round 2
// baseline (312.408 us; speedup 1.0000x reference)
//
#include <hip/hip_runtime.h>

#define BN 1000000
#define KN 16384
#define HN 64

typedef __bf16 bf16x8 __attribute__((ext_vector_type(8)));
typedef float  f32x4  __attribute__((ext_vector_type(4)));

// ---- float32 -> bf16 round-to-nearest-even (values are tame: no NaN/Inf handling) ----
__device__ __forceinline__ unsigned short f2bf(float f) {
    unsigned u = __float_as_uint(f);
    u += 0x7fffu + ((u >> 16) & 1u);
    return (unsigned short)(u >> 16);
}

__device__ __forceinline__ float silu_f(float v) {
    return v / (1.0f + __expf(-v));
}

__device__ __forceinline__ f32x4 mfma16(bf16x8 a, bf16x8 b, f32x4 c) {
    return __builtin_amdgcn_mfma_f32_16x16x32_bf16(a, b, c, 0, 0, 0);
}

// ---- XLA ErfInv32 polynomial (exact match to lax.erf_inv lowering) ----
__device__ __forceinline__ float erfinv_xla(float x) {
    float w = -log1pf(-x * x);
    float p;
    if (w < 5.0f) {
        w -= 2.5f;
        p = 2.81022636e-08f;
        p = fmaf(p, w, 3.43273939e-07f);
        p = fmaf(p, w, -3.5233877e-06f);
        p = fmaf(p, w, -4.39150654e-06f);
        p = fmaf(p, w, 0.00021858087f);
        p = fmaf(p, w, -0.00125372503f);
        p = fmaf(p, w, -0.00417768164f);
        p = fmaf(p, w, 0.246640727f);
        p = fmaf(p, w, 1.50140941f);
    } else {
        w = sqrtf(w) - 3.0f;
        p = -0.000200214257f;
        p = fmaf(p, w, 0.000100950558f);
        p = fmaf(p, w, 0.00134934322f);
        p = fmaf(p, w, -0.00367342844f);
        p = fmaf(p, w, 0.00573950773f);
        p = fmaf(p, w, -0.0076224613f);
        p = fmaf(p, w, 0.00943887047f);
        p = fmaf(p, w, 1.00167406f);
        p = fmaf(p, w, 2.83297682f);
    }
    return p * x;
}

// ---- jax.random.normal(jax.random.key(42), (16384,)), threefry_partitionable=True ----
// 64-bit iota i -> counters (hi=0, lo=i); bits = out0 ^ out1 of threefry2x32-20.
__device__ __forceinline__ float jax_eps16384(int gid) {
    const unsigned k0 = 0u, k1 = 42u, k2 = 0x1BD11BDAu ^ 0u ^ 42u;
    unsigned x0 = 0u + k0;              // hi word of 64-bit iota (= 0 for i < 2^32)
    unsigned x1 = (unsigned)gid + k1;   // lo word
#define TF_RND(r) { x0 += x1; x1 = (x1 << (r)) | (x1 >> (32 - (r))); x1 ^= x0; }
    TF_RND(13) TF_RND(15) TF_RND(26) TF_RND(6)  x0 += k1; x1 += k2 + 1u;
    TF_RND(17) TF_RND(29) TF_RND(16) TF_RND(24) x0 += k2; x1 += k0 + 2u;
    TF_RND(13) TF_RND(15) TF_RND(26) TF_RND(6)  x0 += k0; x1 += k1 + 3u;
    TF_RND(17) TF_RND(29) TF_RND(16) TF_RND(24) x0 += k1; x1 += k2 + 4u;
    TF_RND(13) TF_RND(15) TF_RND(26) TF_RND(6)  x0 += k2; x1 += k0 + 5u;
#undef TF_RND
    unsigned bits = x0 ^ x1;            // 32-bit output: bits1 ^ bits2
    float f = __uint_as_float((bits >> 9) | 0x3f800000u) - 1.0f;   // [0,1)
    const float mn = -0.99999994f;                                  // nextafter(-1,0)
    float u = fmaxf(f * 2.0f + mn, mn);                             // (maxval-minval) rounds to 2.0f
    return 1.41421354f * erfinv_xla(u);                             // float32(sqrt(2))
}

// ============ phase 1: z = silu(silu(x@W1+b1)@W2+b2); atomic segment-sum ============
__global__ __launch_bounds__(256) void k_phase1(
    const float* __restrict__ x, const int* __restrict__ gl,
    const float* __restrict__ W1, const float* __restrict__ b1,
    const float* __restrict__ W2, const float* __restrict__ b2,
    float* __restrict__ gsum, float* __restrict__ counts)
{
    __shared__ __align__(16) unsigned short w1t[64 * 64];   // [j][k] bf16, swizzled
    __shared__ __align__(16) unsigned short w2t[64 * 64];
    __shared__ __align__(16) unsigned short xh[4][64 * 64]; // per-wave x tile, then h1
    __shared__ float b1s[64], b2s[64];
    __shared__ int   glab[256];

    const int t = threadIdx.x;
    const int base = blockIdx.x * 256;

    // stage W1^T, W2^T as bf16 with 16B XOR swizzle (coalesced f32 reads)
    {
        const float4* W1v = (const float4*)W1;
        const float4* W2v = (const float4*)W2;
        #pragma unroll
        for (int i = 0; i < 4; ++i) {
            int e4 = i * 256 + t;         // element e = k*64 + j
            int k  = e4 >> 4;
            int j0 = (e4 & 15) * 4;
            float4 a = W1v[e4];
            float4 b = W2v[e4];
            float av[4] = {a.x, a.y, a.z, a.w};
            float bv[4] = {b.x, b.y, b.z, b.w};
            #pragma unroll
            for (int c = 0; c < 4; ++c) {
                int j = j0 + c;
                int off = j * 128 + ((2 * k) ^ ((j & 7) << 4));
                *(unsigned short*)((char*)w1t + off) = f2bf(av[c]);
                *(unsigned short*)((char*)w2t + off) = f2bf(bv[c]);
            }
        }
    }
    if (t < 64) { b1s[t] = b1[t]; b2s[t] = b2[t]; }
    {   // labels + counts
        int r = base + t;
        int lab = 0;
        if (r < BN) { lab = gl[r]; atomicAdd(&counts[lab], 1.0f); }
        glab[t] = lab;
    }
    // stage x tile (256 rows x 64) f32 -> bf16, swizzled
    for (int i = 0; i < 16; ++i) {
        int e4 = i * 256 + t;             // float4 index: 16 per row
        int rr = e4 >> 4;
        int k4 = (e4 & 15) * 4;
        int r  = base + rr;
        float4 v = make_float4(0.f, 0.f, 0.f, 0.f);
        if (r < BN) v = *(const float4*)(x + (size_t)r * 64 + k4);
        int w = rr >> 6, lr = rr & 63;
        int off = lr * 128 + ((2 * k4) ^ ((lr & 7) << 4));
        ushort4 pk;
        pk.x = f2bf(v.x); pk.y = f2bf(v.y); pk.z = f2bf(v.z); pk.w = f2bf(v.w);
        *(ushort4*)((char*)&xh[w][0] + off) = pk;
    }
    __syncthreads();

    const int wv = t >> 6, lane = t & 63;
    const int lj = lane & 15, lg = lane >> 4;
    unsigned short* myx = &xh[wv][0];

    f32x4 acc[4][4];
    #pragma unroll
    for (int a = 0; a < 4; ++a)
        #pragma unroll
        for (int b = 0; b < 4; ++b) acc[a][b] = f32x4{0.f, 0.f, 0.f, 0.f};

    // ---- layer 1: h1 = silu(x @ W1 + b1) ----
    #pragma unroll
    for (int kk = 0; kk < 2; ++kk) {
        const int kbyte = kk * 64 + lg * 16;
        bf16x8 bw[4];
        #pragma unroll
        for (int ct = 0; ct < 4; ++ct) {
            int row = ct * 16 + lj;
            bw[ct] = *(const bf16x8*)((char*)w1t + row * 128 + (kbyte ^ ((row & 7) << 4)));
        }
        #pragma unroll
        for (int rt = 0; rt < 4; ++rt) {
            int row = rt * 16 + lj;
            bf16x8 aw = *(const bf16x8*)((char*)myx + row * 128 + (kbyte ^ ((row & 7) << 4)));
            #pragma unroll
            for (int ct = 0; ct < 4; ++ct)
                acc[rt][ct] = mfma16(aw, bw[ct], acc[rt][ct]);
        }
    }
    {   // epilogue 1: bias+silu -> bf16 -> own LDS region (C/D: col=l&15, row=(l>>4)*4+reg)
        float bc[4];
        #pragma unroll
        for (int ct = 0; ct < 4; ++ct) bc[ct] = b1s[ct * 16 + lj];
        #pragma unroll
        for (int rt = 0; rt < 4; ++rt) {
            #pragma unroll
            for (int ct = 0; ct < 4; ++ct) {
                f32x4 v = acc[rt][ct];
                #pragma unroll
                for (int rg = 0; rg < 4; ++rg) {
                    int row = rt * 16 + lg * 4 + rg;
                    int col = ct * 16 + lj;
                    float h = silu_f(v[rg] + bc[ct]);
                    int off = row * 128 + ((2 * col) ^ ((row & 7) << 4));
                    *(unsigned short*)((char*)myx + off) = f2bf(h);
                }
                acc[rt][ct] = f32x4{0.f, 0.f, 0.f, 0.f};
            }
        }
    }
    __syncthreads();   // order h1 ds_writes before layer-2 ds_reads

    // ---- layer 2: z = silu(h1 @ W2 + b2) ----
    #pragma unroll
    for (int kk = 0; kk < 2; ++kk) {
        const int kbyte = kk * 64 + lg * 16;
        bf16x8 bw[4];
        #pragma unroll
        for (int ct = 0; ct < 4; ++ct) {
            int row = ct * 16 + lj;
            bw[ct] = *(const bf16x8*)((char*)w2t + row * 128 + (kbyte ^ ((row & 7) << 4)));
        }
        #pragma unroll
        for (int rt = 0; rt < 4; ++rt) {
            int row = rt * 16 + lj;
            bf16x8 aw = *(const bf16x8*)((char*)myx + row * 128 + (kbyte ^ ((row & 7) << 4)));
            #pragma unroll
            for (int ct = 0; ct < 4; ++ct)
                acc[rt][ct] = mfma16(aw, bw[ct], acc[rt][ct]);
        }
    }
    {   // epilogue 2: bias+silu -> atomic segment-sum scatter
        float bc[4];
        #pragma unroll
        for (int ct = 0; ct < 4; ++ct) bc[ct] = b2s[ct * 16 + lj];
        #pragma unroll
        for (int rt = 0; rt < 4; ++rt) {
            int g4[4];
            #pragma unroll
            for (int rg = 0; rg < 4; ++rg) g4[rg] = glab[wv * 64 + rt * 16 + lg * 4 + rg];
            const int rbase = base + wv * 64 + rt * 16 + lg * 4;
            #pragma unroll
            for (int ct = 0; ct < 4; ++ct) {
                f32x4 v = acc[rt][ct];
                const int col = ct * 16 + lj;
                #pragma unroll
                for (int rg = 0; rg < 4; ++rg) {
                    if (rbase + rg < BN) {
                        float z = silu_f(v[rg] + bc[ct]);
                        atomicAdd(&gsum[g4[rg] * 64 + col], z);
                    }
                }
            }
        }
    }
}

// ============ phase 2: group head + reparam sample ============
__global__ __launch_bounds__(64) void k_phase2(
    const float* __restrict__ gsum, const float* __restrict__ counts,
    const float* __restrict__ W3, const float* __restrict__ b3,
    const float* __restrict__ wmu, const float* __restrict__ bmu,
    const float* __restrict__ wlv, const float* __restrict__ blv,
    float* __restrict__ out, float* __restrict__ taug, float* __restrict__ ltaug)
{
    __shared__ __align__(16) float w3t[64 * 64];   // [j][k]
    __shared__ float b3s[64], wmus[64], wlvs[64];
    const int t = threadIdx.x;
    for (int i = 0; i < 64; ++i) w3t[t * 64 + i] = W3[i * 64 + t];  // coalesced read, transposed write
    b3s[t] = b3[t]; wmus[t] = wmu[t]; wlvs[t] = wlv[t];
    __syncthreads();

    const int gid = blockIdx.x * 64 + t;
    const float inv = 1.0f / counts[gid];
    float gf[64];
    #pragma unroll
    for (int i = 0; i < 16; ++i) {
        float4 v = *(const float4*)(gsum + (size_t)gid * 64 + i * 4);
        gf[i * 4 + 0] = v.x * inv; gf[i * 4 + 1] = v.y * inv;
        gf[i * 4 + 2] = v.z * inv; gf[i * 4 + 3] = v.w * inv;
    }
    float mu = bmu[0], lv = blv[0];
    for (int j = 0; j < 64; ++j) {
        float a = b3s[j];
        const float4* wr = (const float4*)(w3t + j * 64);
        #pragma unroll
        for (int k = 0; k < 16; ++k) {
            float4 wv = wr[k];
            a += gf[k * 4 + 0] * wv.x + gf[k * 4 + 1] * wv.y
               + gf[k * 4 + 2] * wv.z + gf[k * 4 + 3] * wv.w;
        }
        float h = silu_f(a);
        mu += h * wmus[j];
        lv += h * wlvs[j];
    }
    lv = fminf(fmaxf(lv, -10.0f), 4.0f);
    float sd  = __expf(0.5f * lv);
    float eps = jax_eps16384(gid);
    float lt  = mu + sd * eps;
    out[gid]      = mu;
    out[KN + gid] = lv;
    taug[gid]  = __expf(lt);
    ltaug[gid] = lt;
}

// ============ phase 3: broadcast per-group sample to reflections ============
__global__ __launch_bounds__(256) void k_phase3(
    const int* __restrict__ gl, const float* __restrict__ taug,
    const float* __restrict__ ltaug, float* __restrict__ out)
{
    int i = blockIdx.x * 256 + threadIdx.x;
    if (i < BN) {
        int g = gl[i];
        out[2 * KN + i]      = taug[g];
        out[2 * KN + BN + i] = ltaug[g];
    }
}

extern "C" void kernel_launch(void* const* d_in, const int* in_sizes, int n_in,
                              void* d_out, int out_size, void* d_ws, size_t ws_size,
                              hipStream_t stream)
{
    const float* x   = (const float*)d_in[0];
    const int*   gl  = (const int*)d_in[1];
    const float* W1  = (const float*)d_in[2];
    const float* b1  = (const float*)d_in[3];
    const float* W2  = (const float*)d_in[4];
    const float* b2  = (const float*)d_in[5];
    const float* W3  = (const float*)d_in[6];
    const float* b3  = (const float*)d_in[7];
    const float* wmu = (const float*)d_in[8];
    const float* bmu = (const float*)d_in[9];
    const float* wlv = (const float*)d_in[10];
    const float* blv = (const float*)d_in[11];
    float* out = (float*)d_out;

    float* ws     = (float*)d_ws;
    float* gsum   = ws;                 // K*H
    float* counts = ws + KN * HN;       // K
    float* taug   = counts + KN;        // K
    float* ltaug  = taug + KN;          // K

    hipMemsetAsync(gsum, 0, (size_t)(KN * HN + KN) * sizeof(float), stream);
    k_phase1<<<(BN + 255) / 256, 256, 0, stream>>>(x, gl, W1, b1, W2, b2, gsum, counts);
    k_phase2<<<KN / 64, 64, 0, stream>>>(gsum, counts, W3, b3, wmu, bmu, wlv, blv, out, taug, ltaug);
    k_phase3<<<(BN + 255) / 256, 256, 0, stream>>>(gl, taug, ltaug, out);
}